// Round 2
// baseline (1005.223 us; speedup 1.0000x reference)
//
#include <hip/hip_runtime.h>
#include <stdint.h>

#define TM 128
#define TN 128
#define BK 64

typedef __attribute__((ext_vector_type(4)))  int i32x4;
typedef __attribute__((ext_vector_type(16))) int i32x16;

__device__ __forceinline__ void async16(const void* g, void* l) {
    __builtin_amdgcn_global_load_lds(
        (const __attribute__((address_space(1))) unsigned int*)g,
        (__attribute__((address_space(3))) unsigned int*)l,
        16 /*bytes*/, 0 /*offset*/, 0 /*aux*/);
}

// Pack int32 (one int8 value per int) -> int8 bytes. Coalesced both sides.
__global__ void pack_both(const int4* __restrict__ sx, int* __restrict__ dx, int nx4,
                          const int4* __restrict__ sw, int* __restrict__ dw, int nw4) {
    int idx    = blockIdx.x * blockDim.x + threadIdx.x;
    int stride = gridDim.x * blockDim.x;
    for (int i = idx; i < nx4; i += stride) {
        int4 a = sx[i];
        dx[i] = (a.x & 0xFF) | ((a.y & 0xFF) << 8) | ((a.z & 0xFF) << 16) | (a.w << 24);
    }
    for (int i = idx; i < nw4; i += stride) {
        int4 a = sw[i];
        dw[i] = (a.x & 0xFF) | ((a.y & 0xFF) << 8) | ((a.z & 0xFF) << 16) | (a.w << 24);
    }
}

// 128x128 tile, BK=64, DOUBLE-BUFFERED LDS (2x16 KB = 32 KB, same footprint as before).
// Pipeline: issue next tile's global_load_lds into buf^1 BEFORE computing current tile
// from buf; single __syncthreads per tile (drains vmcnt -> next buf valid, and fences
// readers of cur before it is overwritten two iterations later). Race-free 2-deep dbuf.
//
// LDS: row-major [128][64 B]; 16B chunk swizzled: phys_chunk = (logical + (row>>1)) & 3.
//   Bank spread proof: byte = row*64 + phys*16 -> 4-bank group g = (4*row + phys) & 7;
//   over 8 consecutive rows at fixed logical chunk, g takes all 8 values.
//   Applied BOTH sides: inverse-swizzled global source (linear LDS dest for
//   global_load_lds) + swizzled ds_read address.
// MFMA 32x32x32 i8: A/B frag = lane[row/col = lane&31][k-half = lane>>5], 16 B.
// C/D: col = lane&31, row = (reg&3) + 8*(reg>>2) + 4*(lane>>5)  (HW-verified).
__global__ __launch_bounds__(256, 2) void w8a8_silu_kernel(
    const int8_t* __restrict__ x, const int8_t* __restrict__ w,
    const float* __restrict__ bias, const float* __restrict__ alpha_p,
    float* __restrict__ out, int M, int N, int K, int nbn)
{
    __shared__ int8_t lds_a[2][TM * BK];   // 2 x 8 KB
    __shared__ int8_t lds_b[2][TN * BK];   // 2 x 8 KB

    const int tid  = threadIdx.x;
    const int lane = tid & 63;
    const int wave = tid >> 6;

    // ---- XCD-aware block swizzle (nwg = 5504, divisible by 8) ----
    int bid = blockIdx.x;
    const int nwg = gridDim.x;
    if ((nwg & 7) == 0) bid = (bid & 7) * (nwg >> 3) + (bid >> 3);
    const int bm = bid / nbn;
    const int bn = bid - bm * nbn;

    // ---- staging: thread -> row (tid>>2) + 64j, phys chunk tid&3 ----
    // stored logical chunk = (phys - (row>>1)) & 3; (row>>1)&3 == (tid>>3)&3 (j-free).
    const int srow  = tid >> 2;                                       // 0..63
    const int skoff = ((((tid & 3) - ((tid >> 3) & 3)) & 3) << 4);    // inverse swizzle
    const int8_t* gA = x + ((size_t)bm * TM + srow) * K + skoff;
    const int8_t* gB = w + ((size_t)bn * TN + srow) * K + skoff;
    const int ldst = tid * 16;           // linear dest: row-major slot for this thread

    // ---- per-wave output subtile (64x64 via 2x2 of 32x32) ----
    const int wr  = (wave >> 1) * 64;
    const int wc  = (wave & 1) * 64;
    const int l31 = lane & 31;
    const int q2  = lane >> 5;
    const int cq  = (l31 >> 1) & 3;      // (row>>1)&3 for this lane's frag rows

    i32x16 acc[2][2] = {};

    const int NT = K / BK;               // 64

    // ---- prologue: stage tile 0 into buf 0 ----
    async16(gA,                  &lds_a[0][ldst]);
    async16(gA + (size_t)64 * K, &lds_a[0][4096 + ldst]);
    async16(gB,                  &lds_b[0][ldst]);
    async16(gB + (size_t)64 * K, &lds_b[0][4096 + ldst]);
    __syncthreads();                     // vmcnt(0) drain + barrier -> buf0 valid

    int cur = 0;
    for (int t = 0; t < NT; ++t) {
        // ---- issue next tile's stage first: overlaps with compute below ----
        if (t + 1 < NT) {
            const size_t kn = (size_t)(t + 1) * BK;
            int8_t* la = lds_a[cur ^ 1];
            int8_t* lb = lds_b[cur ^ 1];
            async16(gA + kn,                  la + ldst);
            async16(gA + (size_t)64 * K + kn, la + 4096 + ldst);
            async16(gB + kn,                  lb + ldst);
            async16(gB + (size_t)64 * K + kn, lb + 4096 + ldst);
        }
        // ---- compute current tile ----
        const int8_t* la = lds_a[cur];
        const int8_t* lb = lds_b[cur];
#pragma unroll
        for (int ks = 0; ks < 2; ++ks) {
            const int ck = (((ks * 2 + q2) + cq) & 3) << 4;   // swizzled chunk offset
            i32x4 a0 = *(const i32x4*)(la + ((wr +      l31) << 6) + ck);
            i32x4 a1 = *(const i32x4*)(la + ((wr + 32 + l31) << 6) + ck);
            i32x4 b0 = *(const i32x4*)(lb + ((wc +      l31) << 6) + ck);
            i32x4 b1 = *(const i32x4*)(lb + ((wc + 32 + l31) << 6) + ck);
            acc[0][0] = __builtin_amdgcn_mfma_i32_32x32x32_i8(a0, b0, acc[0][0], 0, 0, 0);
            acc[0][1] = __builtin_amdgcn_mfma_i32_32x32x32_i8(a0, b1, acc[0][1], 0, 0, 0);
            acc[1][0] = __builtin_amdgcn_mfma_i32_32x32x32_i8(a1, b0, acc[1][0], 0, 0, 0);
            acc[1][1] = __builtin_amdgcn_mfma_i32_32x32x32_i8(a1, b1, acc[1][1], 0, 0, 0);
        }
        __syncthreads();   // drains vmcnt (next buf arrived) + fences readers of cur
        cur ^= 1;
    }

    // ---- epilogue: y = alpha*acc + bias; y*sigmoid(y); fp32 store ----
    const float alpha = *alpha_p;
    const int rowb = bm * TM + wr;
    const int colb = bn * TN + wc;
#pragma unroll
    for (int ct = 0; ct < 2; ++ct) {
        const int col = colb + ct * 32 + l31;
        const float bv = bias[col];
#pragma unroll
        for (int rt = 0; rt < 2; ++rt) {
#pragma unroll
            for (int r = 0; r < 16; ++r) {
                const int row = rowb + rt * 32 + (r & 3) + ((r >> 2) << 3) + (q2 << 2);
                float y = fmaf(alpha, (float)acc[rt][ct][r], bv);
                out[(size_t)row * N + col] = y / (1.0f + __expf(-y));
            }
        }
    }
}

extern "C" void kernel_launch(void* const* d_in, const int* in_sizes, int n_in,
                              void* d_out, int out_size, void* d_ws, size_t ws_size,
                              hipStream_t stream) {
    const int*   x32   = (const int*)d_in[0];     // integer inputs arrive as int32
    const int*   w32   = (const int*)d_in[1];
    const float* bias  = (const float*)d_in[2];
    const float* alpha = (const float*)d_in[3];
    float*       out   = (float*)d_out;

    const int N = in_sizes[2];             // 11008
    const int K = in_sizes[1] / N;         // 4096
    const int M = in_sizes[0] / K;         // 8192

    // pack into workspace: [x8 (M*K)] [w8 (N*K)]
    int8_t* x8 = (int8_t*)d_ws;
    int8_t* w8 = x8 + (size_t)M * K;

    const int nx4 = (int)(((size_t)M * K) / 4);
    const int nw4 = (int)(((size_t)N * K) / 4);
    pack_both<<<2048, 256, 0, stream>>>((const int4*)x32, (int*)x8, nx4,
                                        (const int4*)w32, (int*)w8, nw4);

    const int nbm = M / TM, nbn = N / TN;  // 64, 86 -> 5504 blocks (divisible by 8)
    w8a8_silu_kernel<<<nbm * nbn, 256, 0, stream>>>(x8, w8, bias, alpha, out, M, N, K, nbn);
}

// Round 4
// 960.808 us; speedup vs baseline: 1.0462x; 1.0462x over previous
//
#include <hip/hip_runtime.h>
#include <stdint.h>

#define BM 256
#define BN 256
#define BKB 128            // K-bytes (i8 elems) per tile

typedef __attribute__((ext_vector_type(4)))  int i32x4;
typedef __attribute__((ext_vector_type(16))) int i32x16;

__device__ __forceinline__ void async16(const void* g, void* l) {
    __builtin_amdgcn_global_load_lds(
        (const __attribute__((address_space(1))) unsigned int*)g,
        (__attribute__((address_space(3))) unsigned int*)l,
        16 /*bytes*/, 0 /*offset*/, 0 /*aux*/);
}

// Pack int32 (one int8 value per int) -> int8 bytes. Coalesced both sides.
__global__ void pack_both(const int4* __restrict__ sx, int* __restrict__ dx, int nx4,
                          const int4* __restrict__ sw, int* __restrict__ dw, int nw4) {
    int idx    = blockIdx.x * blockDim.x + threadIdx.x;
    int stride = gridDim.x * blockDim.x;
    for (int i = idx; i < nx4; i += stride) {
        int4 a = sx[i];
        dx[i] = (a.x & 0xFF) | ((a.y & 0xFF) << 8) | ((a.z & 0xFF) << 16) | (a.w << 24);
    }
    for (int i = idx; i < nw4; i += stride) {
        int4 a = sw[i];
        dw[i] = (a.x & 0xFF) | ((a.y & 0xFF) << 8) | ((a.z & 0xFF) << 16) | (a.w << 24);
    }
}

// 256x256 tile, BK=128B, 8 waves (2M x 4N), per-wave 128x64 via 4x2 mfma_i32_32x32x32_i8.
// Phase-split schedule (m201-template port, i8): per K-tile 4 phases (one per k-sub of 32).
// Phase = { 6x ds_read_b128 | stage 4x global_load_lds | s_barrier | lgkmcnt(0)+sched_barrier
//           | setprio(1) 8x MFMA setprio(0) | s_barrier }.
// Raw s_barrier everywhere (no __syncthreads vmcnt-drain); single vmcnt(0) per tile at end
// of phase 3, ~2.5 phases after the prefetch issue -> lands without stalling.
// LDS: 2 buf x (A 32KB + B 32KB) = 128 KiB, 1 block/CU, 2 waves/SIMD.
// Swizzle (both-sides, involution, round-1-verified): row-major [256][128B], 16B chunk
//   phys = logical ^ (row&7); inverse applied on global source, linear gload_lds dest.
// MFMA 32x32x32 i8 frags: lane = [row/col = lane&31][k-half = lane>>5], 16 B.
// C/D: col = lane&31, row = (reg&3) + 8*(reg>>2) + 4*(lane>>5)  (HW-verified).
__global__ __launch_bounds__(512, 2) void w8a8_silu_kernel(
    const int8_t* __restrict__ x, const int8_t* __restrict__ w,
    const float* __restrict__ bias, const float* __restrict__ alpha_p,
    float* __restrict__ out, int M, int N, int K, int nbn)
{
    __shared__ int8_t lds_a[2][BM * BKB];   // 2 x 32 KB
    __shared__ int8_t lds_b[2][BN * BKB];   // 2 x 32 KB

    const int tid  = threadIdx.x;
    const int lane = tid & 63;
    const int wave = tid >> 6;

    // ---- XCD-aware block swizzle (nwg = 1376, divisible by 8) ----
    int bid = blockIdx.x;
    const int nwg = gridDim.x;
    if ((nwg & 7) == 0) bid = (bid & 7) * (nwg >> 3) + (bid >> 3);
    const int bm = bid / nbn;
    const int bn = bid - bm * nbn;

    // ---- staging map: thread -> row (tid>>3) + 64j, phys chunk tid&7 ----
    const int srow  = tid >> 3;                                 // 0..63
    const int skoff = (((tid & 7) ^ ((tid >> 3) & 7)) << 4);    // inverse swizzle
    const int8_t* gA = x + ((size_t)bm * BM + srow) * K + skoff;
    const int8_t* gB = w + ((size_t)bn * BN + srow) * K + skoff;
    const int ldst = tid * 16;

    // ---- per-wave tile: 128 (M) x 64 (N) ----
    const int wr  = (wave >> 2) * 128;
    const int wc  = (wave & 3) * 64;
    const int l31 = lane & 31;
    const int q2  = lane >> 5;
    const int xr  = l31 & 7;          // row&7 for all frag rows (wr, f*32 are mult of 8)

    i32x16 acc[4][2] = {};

    const int NT = K / BKB;           // 32

#define STAGE_A(T, BUF) { const size_t kk = (size_t)(T) * BKB;                       \
    _Pragma("unroll") for (int j = 0; j < 4; ++j)                                     \
        async16(gA + (size_t)(j * 64) * K + kk, &lds_a[BUF][j * 8192 + ldst]); }
#define STAGE_B(T, BUF) { const size_t kk = (size_t)(T) * BKB;                       \
    _Pragma("unroll") for (int j = 0; j < 4; ++j)                                     \
        async16(gB + (size_t)(j * 64) * K + kk, &lds_b[BUF][j * 8192 + ldst]); }

    // ---- prologue: tile 0 -> buf 0 ----
    STAGE_A(0, 0);
    STAGE_B(0, 0);
    asm volatile("s_waitcnt vmcnt(0)" ::: "memory");
    __builtin_amdgcn_s_barrier();

    for (int t = 0; t < NT; ++t) {
        const int cb = t & 1;
        const int8_t* la = lds_a[cb];
        const int8_t* lb = lds_b[cb];
        const bool pf = (t + 1 < NT);

#pragma unroll
        for (int ks = 0; ks < 4; ++ks) {
            // ds-load this k-sub's fragments (reads buf valid since prev tile's ph3)
            i32x4 af[4], bf[2];
            const int ck = ((ks * 2 + q2) ^ xr) << 4;
#pragma unroll
            for (int f = 0; f < 4; ++f)
                af[f] = *(const i32x4*)(la + ((wr + f * 32 + l31) << 7) + ck);
#pragma unroll
            for (int f = 0; f < 2; ++f)
                bf[f] = *(const i32x4*)(lb + ((wc + f * 32 + l31) << 7) + ck);

            // prefetch next tile: A at phase 0, B at phase 1 (front-loaded for slack)
            if (ks == 0 && pf) STAGE_A(t + 1, cb ^ 1);
            if (ks == 1 && pf) STAGE_B(t + 1, cb ^ 1);

            __builtin_amdgcn_s_barrier();
            asm volatile("s_waitcnt lgkmcnt(0)" ::: "memory");
            __builtin_amdgcn_sched_barrier(0);
            __builtin_amdgcn_s_setprio(1);
#pragma unroll
            for (int mf = 0; mf < 4; ++mf)
#pragma unroll
                for (int nf = 0; nf < 2; ++nf)
                    acc[mf][nf] = __builtin_amdgcn_mfma_i32_32x32x32_i8(
                        af[mf], bf[nf], acc[mf][nf], 0, 0, 0);
            __builtin_amdgcn_s_setprio(0);
            __builtin_amdgcn_sched_barrier(0);

            // once per tile, ~2.5 phases after issue: next tile's data landed
            if (ks == 3) asm volatile("s_waitcnt vmcnt(0)" ::: "memory");
            __builtin_amdgcn_s_barrier();
        }
    }

    // ---- epilogue: y = alpha*acc + bias; y*sigmoid(y); fp32 store ----
    const float alpha = *alpha_p;
    const int rowb = bm * BM + wr;
    const int colb = bn * BN + wc;
#pragma unroll
    for (int nf = 0; nf < 2; ++nf) {
        const int col = colb + nf * 32 + l31;
        const float bv = bias[col];
#pragma unroll
        for (int mf = 0; mf < 4; ++mf) {
#pragma unroll
            for (int r = 0; r < 16; ++r) {
                const int row = rowb + mf * 32 + (r & 3) + ((r >> 2) << 3) + (q2 << 2);
                float y = fmaf(alpha, (float)acc[mf][nf][r], bv);
                out[(size_t)row * N + col] = y / (1.0f + __expf(-y));
            }
        }
    }
}

extern "C" void kernel_launch(void* const* d_in, const int* in_sizes, int n_in,
                              void* d_out, int out_size, void* d_ws, size_t ws_size,
                              hipStream_t stream) {
    const int*   x32   = (const int*)d_in[0];     // integer inputs arrive as int32
    const int*   w32   = (const int*)d_in[1];
    const float* bias  = (const float*)d_in[2];
    const float* alpha = (const float*)d_in[3];
    float*       out   = (float*)d_out;

    const int N = in_sizes[2];             // 11008
    const int K = in_sizes[1] / N;         // 4096
    const int M = in_sizes[0] / K;         // 8192

    // pack into workspace: [x8 (M*K)] [w8 (N*K)]
    int8_t* x8 = (int8_t*)d_ws;
    int8_t* w8 = x8 + (size_t)M * K;

    const int nx4 = (int)(((size_t)M * K) / 4);
    const int nw4 = (int)(((size_t)N * K) / 4);
    pack_both<<<2048, 256, 0, stream>>>((const int4*)x32, (int*)x8, nx4,
                                        (const int4*)w32, (int*)w8, nw4);

    const int nbm = M / BM, nbn = N / BN;  // 32, 43 -> 1376 blocks (divisible by 8)
    w8a8_silu_kernel<<<nbm * nbn, 512, 0, stream>>>(x8, w8, bias, alpha, out, M, N, K, nbn);
}

// Round 5
// 949.112 us; speedup vs baseline: 1.0591x; 1.0123x over previous
//
#include <hip/hip_runtime.h>
#include <stdint.h>

#define BM 256
#define BN 256
#define BKB 128            // K-bytes (i8 elems) per tile

typedef __attribute__((ext_vector_type(4)))  int i32x4;
typedef __attribute__((ext_vector_type(16))) int i32x16;

__device__ __forceinline__ void async16(const void* g, void* l) {
    __builtin_amdgcn_global_load_lds(
        (const __attribute__((address_space(1))) unsigned int*)g,
        (__attribute__((address_space(3))) unsigned int*)l,
        16 /*bytes*/, 0 /*offset*/, 0 /*aux*/);
}

// Pack int32 (one int8 value per int) -> int8 bytes. Coalesced both sides.
__global__ void pack_both(const int4* __restrict__ sx, int* __restrict__ dx, int nx4,
                          const int4* __restrict__ sw, int* __restrict__ dw, int nw4) {
    int idx    = blockIdx.x * blockDim.x + threadIdx.x;
    int stride = gridDim.x * blockDim.x;
    for (int i = idx; i < nx4; i += stride) {
        int4 a = sx[i];
        dx[i] = (a.x & 0xFF) | ((a.y & 0xFF) << 8) | ((a.z & 0xFF) << 16) | (a.w << 24);
    }
    for (int i = idx; i < nw4; i += stride) {
        int4 a = sw[i];
        dw[i] = (a.x & 0xFF) | ((a.y & 0xFF) << 8) | ((a.z & 0xFF) << 16) | (a.w << 24);
    }
}

// 256x256 tile, BK=128B, 8 waves (2M x 4N), per-wave 128x64 via 4x2 mfma_i32_32x32x32_i8.
// Round-5 schedule: NO intra-tile barriers (all 4 k-subs read the same LDS buffer, valid
// for the whole tile). Per tile: read frags[0]; issue next tile's 8 global_load_lds;
// then unrolled ks-loop with fragment DOUBLE-BUFFER: read frags[ks+1] BEFORE the 8-MFMA
// cluster of ks, so the compiler's fine-grained lgkmcnt waits let ds_read (LDS pipe) fly
// under MFMA (matrix pipe). One vmcnt(0)+s_barrier per tile (prefetch issued ~2300 cyc
// earlier -> lands free). Waves skew freely within a tile -> cross-wave pipe overlap too.
// LDS: 2 buf x (A 32KB + B 32KB) = 128 KiB, 1 block/CU, 2 waves/SIMD.
// Swizzle (both-sides involution): row-major [256][128B], 16B chunk phys = logical ^
//   (row&7); inverse on global source (linear gload_lds dest), XOR on ds_read address.
// MFMA 32x32x32 i8 frags: lane = [row/col = lane&31][k-half = lane>>5], 16 B.
// C/D: col = lane&31, row = (reg&3) + 8*(reg>>2) + 4*(lane>>5)  (HW-verified).
__global__ __launch_bounds__(512, 2) void w8a8_silu_kernel(
    const int8_t* __restrict__ x, const int8_t* __restrict__ w,
    const float* __restrict__ bias, const float* __restrict__ alpha_p,
    float* __restrict__ out, int M, int N, int K, int nbn)
{
    __shared__ int8_t lds_a[2][BM * BKB];   // 2 x 32 KB
    __shared__ int8_t lds_b[2][BN * BKB];   // 2 x 32 KB

    const int tid  = threadIdx.x;
    const int lane = tid & 63;
    const int wave = tid >> 6;

    // ---- XCD-aware block swizzle (nwg = 1376, divisible by 8) ----
    int bid = blockIdx.x;
    const int nwg = gridDim.x;
    if ((nwg & 7) == 0) bid = (bid & 7) * (nwg >> 3) + (bid >> 3);
    const int bm = bid / nbn;
    const int bn = bid - bm * nbn;

    // ---- staging map: thread -> row (tid>>3) + 64j, phys chunk tid&7 ----
    const int srow  = tid >> 3;                                 // 0..63
    const int skoff = (((tid & 7) ^ ((tid >> 3) & 7)) << 4);    // inverse swizzle
    const int8_t* gA = x + ((size_t)bm * BM + srow) * K + skoff;
    const int8_t* gB = w + ((size_t)bn * BN + srow) * K + skoff;
    const int ldst = tid * 16;

    // ---- per-wave tile: 128 (M) x 64 (N) ----
    const int wr  = (wave >> 2) * 128;
    const int wc  = (wave & 3) * 64;
    const int l31 = lane & 31;
    const int q2  = lane >> 5;
    const int xr  = l31 & 7;          // row&7 for all frag rows (wr, f*32 are mult of 8)

    i32x16 acc[4][2] = {};

    const int NT = K / BKB;           // 32

#define STAGE_A(T, BUF) { const size_t kk = (size_t)(T) * BKB;                       \
    _Pragma("unroll") for (int j = 0; j < 4; ++j)                                     \
        async16(gA + (size_t)(j * 64) * K + kk, &lds_a[BUF][j * 8192 + ldst]); }
#define STAGE_B(T, BUF) { const size_t kk = (size_t)(T) * BKB;                       \
    _Pragma("unroll") for (int j = 0; j < 4; ++j)                                     \
        async16(gB + (size_t)(j * 64) * K + kk, &lds_b[BUF][j * 8192 + ldst]); }

// read the 6 fragments (4 A + 2 B) of k-sub KS into frag slot S
#define READF(S, KS) {                                                                \
    const int ck_ = (((KS) * 2 + q2) ^ xr) << 4;                                      \
    _Pragma("unroll") for (int f = 0; f < 4; ++f)                                     \
        af[S][f] = *(const i32x4*)(la + ((wr + f * 32 + l31) << 7) + ck_);            \
    _Pragma("unroll") for (int f = 0; f < 2; ++f)                                     \
        bf[S][f] = *(const i32x4*)(lb + ((wc + f * 32 + l31) << 7) + ck_); }

    // ---- prologue: tile 0 -> buf 0 ----
    STAGE_A(0, 0);
    STAGE_B(0, 0);
    asm volatile("s_waitcnt vmcnt(0)" ::: "memory");
    __builtin_amdgcn_s_barrier();

    for (int t = 0; t < NT; ++t) {
        const int cb = t & 1;
        const int8_t* la = lds_a[cb];
        const int8_t* lb = lds_b[cb];

        i32x4 af[2][4], bf[2][2];
        READF(0, 0);
        if (t + 1 < NT) {               // prefetch next tile while computing this one
            STAGE_A(t + 1, cb ^ 1);
            STAGE_B(t + 1, cb ^ 1);
        }

#pragma unroll
        for (int ks = 0; ks < 4; ++ks) {
            const int cu = ks & 1;
            if (ks < 3) { const int nx = cu ^ 1; READF(nx, ks + 1); }
            __builtin_amdgcn_s_setprio(1);
#pragma unroll
            for (int mf = 0; mf < 4; ++mf)
#pragma unroll
                for (int nf = 0; nf < 2; ++nf)
                    acc[mf][nf] = __builtin_amdgcn_mfma_i32_32x32x32_i8(
                        af[cu][mf], bf[cu][nf], acc[mf][nf], 0, 0, 0);
            __builtin_amdgcn_s_setprio(0);
        }

        // next tile's prefetch has landed (issued ~2300 cyc ago); swap buffers
        asm volatile("s_waitcnt vmcnt(0)" ::: "memory");
        __builtin_amdgcn_s_barrier();
        __builtin_amdgcn_sched_barrier(0);
    }

    // ---- epilogue: y = alpha*acc + bias; y*sigmoid(y); fp32 store ----
    const float alpha = *alpha_p;
    const int rowb = bm * BM + wr;
    const int colb = bn * BN + wc;
#pragma unroll
    for (int nf = 0; nf < 2; ++nf) {
        const int col = colb + nf * 32 + l31;
        const float bv = bias[col];
#pragma unroll
        for (int mf = 0; mf < 4; ++mf) {
#pragma unroll
            for (int r = 0; r < 16; ++r) {
                const int row = rowb + mf * 32 + (r & 3) + ((r >> 2) << 3) + (q2 << 2);
                float y = fmaf(alpha, (float)acc[mf][nf][r], bv);
                out[(size_t)row * N + col] = y / (1.0f + __expf(-y));
            }
        }
    }
}

extern "C" void kernel_launch(void* const* d_in, const int* in_sizes, int n_in,
                              void* d_out, int out_size, void* d_ws, size_t ws_size,
                              hipStream_t stream) {
    const int*   x32   = (const int*)d_in[0];     // integer inputs arrive as int32
    const int*   w32   = (const int*)d_in[1];
    const float* bias  = (const float*)d_in[2];
    const float* alpha = (const float*)d_in[3];
    float*       out   = (float*)d_out;

    const int N = in_sizes[2];             // 11008
    const int K = in_sizes[1] / N;         // 4096
    const int M = in_sizes[0] / K;         // 8192

    // pack into workspace: [x8 (M*K)] [w8 (N*K)]
    int8_t* x8 = (int8_t*)d_ws;
    int8_t* w8 = x8 + (size_t)M * K;

    const int nx4 = (int)(((size_t)M * K) / 4);
    const int nw4 = (int)(((size_t)N * K) / 4);
    pack_both<<<2048, 256, 0, stream>>>((const int4*)x32, (int*)x8, nx4,
                                        (const int4*)w32, (int*)w8, nw4);

    const int nbm = M / BM, nbn = N / BN;  // 32, 43 -> 1376 blocks (divisible by 8)
    w8a8_silu_kernel<<<nbm * nbn, 512, 0, stream>>>(x8, w8, bias, alpha, out, M, N, K, nbn);
}